// Round 9
// baseline (187.191 us; speedup 1.0000x reference)
//
#include <hip/hip_runtime.h>

// Fused: z = x @ W^T + b_lin; y = swish(z) + b_ex; GroupNorm(32 groups) * gn_w + gn_b
// x: [8192, 2048] f32, W: [4096, 2048] f32, out: [8192, 4096] f32
// Round 9: fragment reads via INLINE-ASM ds_read_b128 so the compiler cannot
// see an LDS RAW hazard vs global_load_lds and cannot insert vmcnt(0) drains
// per phase (the R2-R8 28%-MfmaUtil invariant). Counted vmcnt gates now real.

typedef __attribute__((ext_vector_type(8))) short short8;
typedef __attribute__((ext_vector_type(4))) float f32x4;

#define M_DIM 8192
#define N_DIM 4096
#define K_DIM 2048
#define BM 256
#define BN 256
#define BK 64
#define NT (K_DIM / BK)  // 32

#define AS1 __attribute__((address_space(1)))
#define AS3 __attribute__((address_space(3)))

// ---------------- f32 -> bf16 (RNE) convert, 8 elems/thread ----------------
__global__ void f32_to_bf16_k(const float* __restrict__ in, ushort* __restrict__ out, int n8) {
    int i = blockIdx.x * blockDim.x + threadIdx.x;
    if (i >= n8) return;
    const float4* p = (const float4*)in + 2 * (size_t)i;
    float4 a = p[0], b = p[1];
    float v[8] = {a.x, a.y, a.z, a.w, b.x, b.y, b.z, b.w};
    ushort rr[8];
#pragma unroll
    for (int j = 0; j < 8; ++j) {
        unsigned u = __float_as_uint(v[j]);
        rr[j] = (ushort)((u + 0x7fffu + ((u >> 16) & 1u)) >> 16);  // RNE
    }
    uint4 o;
    o.x = (unsigned)rr[0] | ((unsigned)rr[1] << 16);
    o.y = (unsigned)rr[2] | ((unsigned)rr[3] << 16);
    o.z = (unsigned)rr[4] | ((unsigned)rr[5] << 16);
    o.w = (unsigned)rr[6] | ((unsigned)rr[7] << 16);
    ((uint4*)out)[i] = o;
}

// LDS: 2 buffers x 64KB. Buffer (ushort offsets): A [0,16384), B [16384,32768);
// 256 rows x 64 ushorts (128B rows, kk0|kk1 halves in-row).
// Read swizzle: 16B-slot = (kk*4+h) ^ (r&7)  [proven 0-conflict R5/R6/R8].
// Staged linearly (global_load_lds); global SOURCE col pre-swizzled.

#define BAR() __builtin_amdgcn_s_barrier()
#define VMC(n_) asm volatile("s_waitcnt vmcnt(" #n_ ")" ::: "memory")
#define LGKM0() do { asm volatile("s_waitcnt lgkmcnt(0)" ::: "memory"); \
                     __builtin_amdgcn_sched_barrier(0); } while (0)
// asm ds_read: invisible to alias analysis (the whole point)
#define DSR(dst, base, OFFLIT) \
    asm volatile("ds_read_b128 %0, %1 offset:" OFFLIT : "=v"(dst) : "v"(base))

__global__ __launch_bounds__(512, 2) void gemm_swish_gn(
    const ushort* __restrict__ xb, const ushort* __restrict__ wb,
    const float* __restrict__ bias_lin, const float* __restrict__ bias_extra,
    const float* __restrict__ gn_w, const float* __restrict__ gn_b,
    float* __restrict__ out)
{
    extern __shared__ __align__(16) ushort lds[];  // 2 x 32768 ushorts

    const int t = threadIdx.x;
    const int w = t >> 6;
    const int l = t & 63;
    const int wm = w >> 2;   // 0..1
    const int wn = w & 3;    // 0..3
    const int h = l >> 4;    // 0..3
    const int r = l & 15;    // 0..15

    // T1: XCD swizzle (512 blocks, bijective)
    const int bid = blockIdx.x;
    const int id = (bid & 7) * 64 + (bid >> 3);
    const int brow = id & 31;   // M tile
    const int bcol = id >> 5;   // N tile (= 2 GroupNorm groups)

    // ---- staging: thread t covers row s=t>>3 (per 64-row round), 16B slot t&7,
    // source col pre-swizzled by slot ^= (row&7).
    const int s = t >> 3;
    const int scol = (((t & 7) ^ (s & 7)) << 3);            // ushorts
    const ushort* pA = xb + (size_t)(brow * BM + s) * K_DIM + scol;
    const int rB = (s & 31) + ((s >> 5) << 6);              // B scattered rows
    const ushort* pB = wb + (size_t)(bcol * BN + rB) * K_DIM + scol;
    const int dstA = t * 8;
    const int dstB = rB * 64 + ((t & 7) << 3);

    // chunk rounds: A-lo ROFF {0,128}; A-hi {64,192}; B-lo {0,128}; B-hi {32,160}
#define STG_A(P, ROFF) __builtin_amdgcn_global_load_lds(                         \
        (const AS1 void*)(pA + (size_t)(ROFF) * K_DIM),                          \
        (AS3 void*)&lds[(P) * 32768 + (ROFF) * 64 + dstA], 16, 0, 0)
#define STG_B(P, ROFF) __builtin_amdgcn_global_load_lds(                         \
        (const AS1 void*)(pB + (size_t)(ROFF) * K_DIM),                          \
        (AS3 void*)&lds[(P) * 32768 + 16384 + (ROFF) * 64 + dstB], 16, 0, 0)

    // fragment read byte-addresses: row*128 + ((kk*64 + h*16) ^ (r&7)*16)
    const int xr16 = (r & 7) << 4;
    const uint ldsbase = (uint)(size_t)&lds[0];
    const uint aK0_0 = ldsbase + (uint)((wm * 128 + r) * 128 + ((h << 4) ^ xr16));
    const uint aK1_0 = aK0_0 ^ 64;                 // kk1: slot bit2 flip
    const uint bK0_0 = ldsbase + 32768u + (uint)((wn * 64 + r) * 128 + ((h << 4) ^ xr16));
    const uint bK1_0 = bK0_0 ^ 64;
    const uint aK0_1 = aK0_0 + 65536u;             // buffer 1
    const uint aK1_1 = aK1_0 + 65536u;
    const uint bK0_1 = bK0_0 + 65536u;
    const uint bK1_1 = bK1_0 + 65536u;

    f32x4 acc[8][4];
#pragma unroll
    for (int m = 0; m < 8; ++m)
#pragma unroll
        for (int n = 0; n < 4; ++n)
            acc[m][n] = f32x4{0.f, 0.f, 0.f, 0.f};

    // ---- prologue: stage tile 0 (Alo, Blo, Bhi, Ahi), gate, BAR
    STG_A(0, 0); STG_A(0, 128);   // Alo
    STG_B(0, 0); STG_B(0, 128);   // Blo
    STG_B(0, 32); STG_B(0, 160);  // Bhi
    STG_A(0, 64); STG_A(0, 192);  // Ahi
    pA += BK; pB += BK;
    VMC(4);                        // Alo0, Blo0 landed
    BAR();

    short8 aF[4][2], bF[4][2];

#define MFMA(mm, nn, kk, ai) \
    acc[mm][nn] = __builtin_amdgcn_mfma_f32_16x16x32_bf16(aF[ai][kk], bF[nn][kk], acc[mm][nn], 0, 0, 0)

    // Phase = { asm reads(this); stage(next); gate; BAR; LGKM0; 16 MFMA }.
    // Stages: ph1 Alo', ph2 Blo'+Bhi', ph3 Ahi'. Gates steady: ph1 VMC(4),
    // ph2 VMC(6), ph4 VMC(4); tail tile: VMC(2)/VMC(0)/none (derived R6/R8).
#define DO_TILE(AK0, AK1, BK0, BK1, P, tt)                                          \
  {                                                                                 \
    /* ---- ph1: reads Alo(m0-3 kk0/1)+Blo(n0-1); stage Alo' ---- */                \
    DSR(aF[0][0], AK0, "0");     DSR(aF[0][1], AK1, "0");                           \
    DSR(aF[1][0], AK0, "2048");  DSR(aF[1][1], AK1, "2048");                        \
    DSR(aF[2][0], AK0, "4096");  DSR(aF[2][1], AK1, "4096");                        \
    DSR(aF[3][0], AK0, "6144");  DSR(aF[3][1], AK1, "6144");                        \
    DSR(bF[0][0], BK0, "0");     DSR(bF[0][1], BK1, "0");                           \
    DSR(bF[1][0], BK0, "2048");  DSR(bF[1][1], BK1, "2048");                        \
    if ((tt) != NT - 1) { STG_A((P) ^ 1, 0); STG_A((P) ^ 1, 128); }                 \
    if ((tt) == NT - 1) { VMC(2); } else { VMC(4); }                                \
    BAR(); LGKM0();                                                                 \
    __builtin_amdgcn_s_setprio(1);                                                  \
    _Pragma("unroll") for (int kk = 0; kk < 2; ++kk)                                \
        _Pragma("unroll") for (int m = 0; m < 4; ++m)                               \
            _Pragma("unroll") for (int n = 0; n < 2; ++n)                           \
                MFMA(m, n, kk, m);                                                  \
    __builtin_amdgcn_s_setprio(0);                                                  \
    /* ---- ph2: reads Bhi(n2-3); stage Blo'+Bhi' ---- */                           \
    DSR(bF[2][0], BK0, "4096");  DSR(bF[2][1], BK1, "4096");                        \
    DSR(bF[3][0], BK0, "6144");  DSR(bF[3][1], BK1, "6144");                        \
    if ((tt) != NT - 1) { STG_B((P) ^ 1, 0); STG_B((P) ^ 1, 128);                   \
                          STG_B((P) ^ 1, 32); STG_B((P) ^ 1, 160); }                \
    if ((tt) == NT - 1) { VMC(0); } else { VMC(6); }                                \
    BAR(); LGKM0();                                                                 \
    __builtin_amdgcn_s_setprio(1);                                                  \
    _Pragma("unroll") for (int kk = 0; kk < 2; ++kk)                                \
        _Pragma("unroll") for (int m = 0; m < 4; ++m)                               \
            _Pragma("unroll") for (int n = 2; n < 4; ++n)                           \
                MFMA(m, n, kk, m);                                                  \
    __builtin_amdgcn_s_setprio(0);                                                  \
    /* ---- ph3: reads Ahi(m4-7); stage Ahi' ---- */                                \
    DSR(aF[0][0], AK0, "8192");  DSR(aF[0][1], AK1, "8192");                        \
    DSR(aF[1][0], AK0, "10240"); DSR(aF[1][1], AK1, "10240");                       \
    DSR(aF[2][0], AK0, "12288"); DSR(aF[2][1], AK1, "12288");                       \
    DSR(aF[3][0], AK0, "14336"); DSR(aF[3][1], AK1, "14336");                       \
    if ((tt) != NT - 1) { STG_A((P) ^ 1, 64); STG_A((P) ^ 1, 192);                  \
                          pA += BK; pB += BK; }                                     \
    BAR(); LGKM0();                                                                 \
    __builtin_amdgcn_s_setprio(1);                                                  \
    _Pragma("unroll") for (int kk = 0; kk < 2; ++kk)                                \
        _Pragma("unroll") for (int m = 4; m < 8; ++m)                               \
            _Pragma("unroll") for (int n = 0; n < 2; ++n)                           \
                MFMA(m, n, kk, m - 4);                                              \
    __builtin_amdgcn_s_setprio(0);                                                  \
    /* ---- ph4: register-only; gate next tile's ph1 ---- */                        \
    if ((tt) < NT - 1) { VMC(4); }                                                  \
    BAR();                                                                          \
    __builtin_amdgcn_s_setprio(1);                                                  \
    _Pragma("unroll") for (int kk = 0; kk < 2; ++kk)                                \
        _Pragma("unroll") for (int m = 4; m < 8; ++m)                               \
            _Pragma("unroll") for (int n = 2; n < 4; ++n)                           \
                MFMA(m, n, kk, m - 4);                                              \
    __builtin_amdgcn_s_setprio(0);                                                  \
  }

#pragma unroll 1
    for (int tp = 0; tp < NT; tp += 2) {
        DO_TILE(aK0_0, aK1_0, bK0_0, bK1_0, 0, tp);
        DO_TILE(aK0_1, aK1_1, bK0_1, bK1_1, 1, tp + 1);
    }

    // ---- epilogue: bias + swish + extra bias, GroupNorm per 128-col group ----
    // acc[m][n][j]: row = wm*128 + m*16 + h*4 + j, col = wn*64 + n*16 + r
    const int colbase = bcol * BN + wn * 64;
    float bl[4], be[4], gwv[4], gbv[4];
#pragma unroll
    for (int n = 0; n < 4; ++n) {
        int col = colbase + n * 16 + r;
        bl[n] = bias_lin[col];
        be[n] = bias_extra[col];
        gwv[n] = gn_w[col];
        gbv[n] = gn_b[col];
    }

    float s1[8][4], s2[8][4];
#pragma unroll
    for (int m = 0; m < 8; ++m)
#pragma unroll
        for (int j = 0; j < 4; ++j) { s1[m][j] = 0.f; s2[m][j] = 0.f; }

#pragma unroll
    for (int m = 0; m < 8; ++m)
#pragma unroll
        for (int n = 0; n < 4; ++n)
#pragma unroll
            for (int j = 0; j < 4; ++j) {
                float z = acc[m][n][j] + bl[n];
                float sw = z / (1.f + __expf(-z)) + be[n];
                acc[m][n][j] = sw;
                s1[m][j] += sw;
                s2[m][j] += sw * sw;
            }

#pragma unroll
    for (int mask = 1; mask < 16; mask <<= 1) {
#pragma unroll
        for (int m = 0; m < 8; ++m)
#pragma unroll
            for (int j = 0; j < 4; ++j) {
                s1[m][j] += __shfl_xor(s1[m][j], mask, 16);
                s2[m][j] += __shfl_xor(s2[m][j], mask, 16);
            }
    }

    __syncthreads();  // all asm ds_reads drained (per-phase LGKM0); safe to alias
    float* sred = (float*)lds;  // [2 stat][2 group-half][2 wave-pair][256 rows]
    const int gh = wn >> 1;
    const int p = wn & 1;
    if (r == 0) {
#pragma unroll
        for (int m = 0; m < 8; ++m)
#pragma unroll
            for (int j = 0; j < 4; ++j) {
                int row = wm * 128 + m * 16 + h * 4 + j;
                sred[((0 * 2 + gh) * 2 + p) * 256 + row] = s1[m][j];
                sred[((1 * 2 + gh) * 2 + p) * 256 + row] = s2[m][j];
            }
    }
    __syncthreads();

    const size_t orow0 = (size_t)brow * BM;
#pragma unroll
    for (int m = 0; m < 8; ++m)
#pragma unroll
        for (int j = 0; j < 4; ++j) {
            int row = wm * 128 + m * 16 + h * 4 + j;
            float mu = (sred[((0 * 2 + gh) * 2 + 0) * 256 + row] +
                        sred[((0 * 2 + gh) * 2 + 1) * 256 + row]) * (1.f / 128.f);
            float ex2 = (sred[((1 * 2 + gh) * 2 + 0) * 256 + row] +
                         sred[((1 * 2 + gh) * 2 + 1) * 256 + row]) * (1.f / 128.f);
            float var = ex2 - mu * mu;
            float rs = rsqrtf(var + 1e-5f);
            float* orow = out + (orow0 + row) * N_DIM;
#pragma unroll
            for (int n = 0; n < 4; ++n) {
                int col = colbase + n * 16 + r;
                orow[col] = (acc[m][n][j] - mu) * rs * gwv[n] + gbv[n];
            }
        }
}

extern "C" void kernel_launch(void* const* d_in, const int* in_sizes, int n_in,
                              void* d_out, int out_size, void* d_ws, size_t ws_size,
                              hipStream_t stream) {
    const float* x        = (const float*)d_in[0];
    const float* weight   = (const float*)d_in[1];
    const float* bias_lin = (const float*)d_in[2];
    const float* bias_ex  = (const float*)d_in[3];
    const float* gn_w     = (const float*)d_in[4];
    const float* gn_b     = (const float*)d_in[5];
    float* out = (float*)d_out;

    ushort* xb = (ushort*)d_ws;                     // 32 MiB bf16
    ushort* wb = xb + (size_t)M_DIM * K_DIM;        // 16 MiB bf16

    {
        int n8 = (M_DIM * K_DIM) / 8;
        f32_to_bf16_k<<<n8 / 256, 256, 0, stream>>>(x, xb, n8);
    }
    {
        int n8 = (N_DIM * K_DIM) / 8;
        f32_to_bf16_k<<<n8 / 256, 256, 0, stream>>>(weight, wb, n8);
    }

    (void)hipFuncSetAttribute((const void*)gemm_swish_gn,
                              hipFuncAttributeMaxDynamicSharedMemorySize, 131072);

    dim3 grid((M_DIM / BM) * (N_DIM / BN));  // 512 blocks
    gemm_swish_gn<<<grid, 512, 131072, stream>>>(xb, wb, bias_lin, bias_ex, gn_w, gn_b, out);
}

// Round 10
// 182.006 us; speedup vs baseline: 1.0285x; 1.0285x over previous
//
#include <hip/hip_runtime.h>

// Fused: z = x @ W^T + b_lin; y = swish(z) + b_ex; GroupNorm(32 groups) * gn_w + gn_b
// x: [8192, 2048] f32, W: [4096, 2048] f32, out: [8192, 4096] f32
// Round 10: m97-replica concurrency structure. 128x128 tile, BK=64, 4 waves,
// SINGLE 32KB LDS buffer (+2KB stats) -> 4 blocks/CU co-resident; plain
// __syncthreads 2-barrier K-loop; no asm/setprio/vmcnt. Inter-block overlap
// (m114/m97 mechanism) covers barrier drains. Proven 0-conflict LDS layout.

typedef __attribute__((ext_vector_type(8))) short short8;
typedef __attribute__((ext_vector_type(4))) float f32x4;

#define M_DIM 8192
#define N_DIM 4096
#define K_DIM 2048
#define BM 128
#define BN 128
#define BK 64
#define NT (K_DIM / BK)  // 32

#define AS1 __attribute__((address_space(1)))
#define AS3 __attribute__((address_space(3)))

// ---------------- f32 -> bf16 (RNE) convert, 8 elems/thread ----------------
__global__ void f32_to_bf16_k(const float* __restrict__ in, ushort* __restrict__ out, int n8) {
    int i = blockIdx.x * blockDim.x + threadIdx.x;
    if (i >= n8) return;
    const float4* p = (const float4*)in + 2 * (size_t)i;
    float4 a = p[0], b = p[1];
    float v[8] = {a.x, a.y, a.z, a.w, b.x, b.y, b.z, b.w};
    ushort rr[8];
#pragma unroll
    for (int j = 0; j < 8; ++j) {
        unsigned u = __float_as_uint(v[j]);
        rr[j] = (ushort)((u + 0x7fffu + ((u >> 16) & 1u)) >> 16);  // RNE
    }
    uint4 o;
    o.x = (unsigned)rr[0] | ((unsigned)rr[1] << 16);
    o.y = (unsigned)rr[2] | ((unsigned)rr[3] << 16);
    o.z = (unsigned)rr[4] | ((unsigned)rr[5] << 16);
    o.w = (unsigned)rr[6] | ((unsigned)rr[7] << 16);
    ((uint4*)out)[i] = o;
}

// LDS (ushort offsets): A [0,8192): 128 rows x 64 sh (128B rows, kk0|kk1
// halves in-row); B [8192,16384); stats floats at 16384 (2KB).
// 16B-slot stored at (row,s) holds k-chunk s ^ (row&7); read uses slot
// (kk*4+h) ^ (r&7)  [0-conflict, proven R5/R6/R8/R9]. Source pre-swizzled.

__global__ __launch_bounds__(256, 3) void gemm_swish_gn(
    const ushort* __restrict__ xb, const ushort* __restrict__ wb,
    const float* __restrict__ bias_lin, const float* __restrict__ bias_extra,
    const float* __restrict__ gn_w, const float* __restrict__ gn_b,
    float* __restrict__ out)
{
    extern __shared__ __align__(16) ushort lds[];

    const int t = threadIdx.x;
    const int w = t >> 6;        // 4 waves: 2M x 2N
    const int l = t & 63;
    const int wm = w >> 1;       // 0..1
    const int wn = w & 1;        // 0..1
    const int h = l >> 4;        // 0..3
    const int r = l & 15;        // 0..15

    // XCD swizzle: 2048 blocks; 8 XCDs as 4x2 grid of 16x16-tile patches.
    const int bid = blockIdx.x;
    const int xcd = bid & 7;
    const int pp = bid >> 3;                      // 0..255
    const int brow = (xcd & 3) * 16 + (pp & 15);  // 0..63
    const int bcol = (xcd >> 2) * 16 + (pp >> 4); // 0..31  (= GN group)

    // ---- staging: thread t -> row s=t>>3 (32 rows/round), slot t&7;
    // source col pre-swizzled: slot ^= (s&7).
    const int s = t >> 3;
    const int scol = (((t & 7) ^ (s & 7)) << 3);  // ushorts
    const ushort* pA = xb + (size_t)(brow * BM + s) * K_DIM + scol;
    const ushort* pB = wb + (size_t)(bcol * BN + s) * K_DIM + scol;
    const int dst = t * 8;

#define STG_A(ROFF) __builtin_amdgcn_global_load_lds(                          \
        (const AS1 void*)(pA + (size_t)(ROFF) * K_DIM),                        \
        (AS3 void*)&lds[(ROFF) * 64 + dst], 16, 0, 0)
#define STG_B(ROFF) __builtin_amdgcn_global_load_lds(                          \
        (const AS1 void*)(pB + (size_t)(ROFF) * K_DIM),                        \
        (AS3 void*)&lds[8192 + (ROFF) * 64 + dst], 16, 0, 0)

    // fragment read offsets (ushorts): row*64 + ((kk*32 + h*8) ^ (r&7)*8)
    const int xr8 = (r & 7) << 3;
    const int aOff0 = (wm * 64 + r) * 64 + ((h << 3) ^ xr8);   // + m*1024
    const int aOff1 = aOff0 ^ 32;                              // kk1
    const int bOff0 = 8192 + (wn * 64 + r) * 64 + ((h << 3) ^ xr8);
    const int bOff1 = bOff0 ^ 32;

    f32x4 acc[4][4];
#pragma unroll
    for (int m = 0; m < 4; ++m)
#pragma unroll
        for (int n = 0; n < 4; ++n)
            acc[m][n] = f32x4{0.f, 0.f, 0.f, 0.f};

    short8 aF[4][2], bF[4][2];

#pragma unroll 1
    for (int kt = 0; kt < NT; ++kt) {
        // ---- stage tile kt (8 x gload_lds w16) ----
        STG_A(0); STG_A(32); STG_A(64); STG_A(96);
        STG_B(0); STG_B(32); STG_B(64); STG_B(96);
        pA += BK; pB += BK;
        __syncthreads();   // compiler drains vmcnt -> LDS writes visible

        // ---- read fragments + 32 MFMA ----
#pragma unroll
        for (int m = 0; m < 4; ++m) {
            aF[m][0] = *(const short8*)&lds[aOff0 + m * 1024];
            aF[m][1] = *(const short8*)&lds[aOff1 + m * 1024];
        }
#pragma unroll
        for (int n = 0; n < 4; ++n) {
            bF[n][0] = *(const short8*)&lds[bOff0 + n * 1024];
            bF[n][1] = *(const short8*)&lds[bOff1 + n * 1024];
        }
#pragma unroll
        for (int kk = 0; kk < 2; ++kk)
#pragma unroll
            for (int m = 0; m < 4; ++m)
#pragma unroll
                for (int n = 0; n < 4; ++n)
                    acc[m][n] = __builtin_amdgcn_mfma_f32_16x16x32_bf16(
                        aF[m][kk], bF[n][kk], acc[m][n], 0, 0, 0);

        __syncthreads();   // reads done before next stage overwrites
    }

    // ---- epilogue: bias + swish + extra bias; GroupNorm (group == block cols)
    // acc[m][n][j]: row = wm*64 + m*16 + h*4 + j, col = wn*64 + n*16 + r
    const int colbase = bcol * BN + wn * 64;
    float bl[4], be[4], gwv[4], gbv[4];
#pragma unroll
    for (int n = 0; n < 4; ++n) {
        int col = colbase + n * 16 + r;
        bl[n] = bias_lin[col];
        be[n] = bias_extra[col];
        gwv[n] = gn_w[col];
        gbv[n] = gn_b[col];
    }

    float s1[4][4], s2[4][4];
#pragma unroll
    for (int m = 0; m < 4; ++m)
#pragma unroll
        for (int j = 0; j < 4; ++j) { s1[m][j] = 0.f; s2[m][j] = 0.f; }

#pragma unroll
    for (int m = 0; m < 4; ++m)
#pragma unroll
        for (int n = 0; n < 4; ++n)
#pragma unroll
            for (int j = 0; j < 4; ++j) {
                float z = acc[m][n][j] + bl[n];
                float sw = z / (1.f + __expf(-z)) + be[n];
                acc[m][n][j] = sw;
                s1[m][j] += sw;
                s2[m][j] += sw * sw;
            }

#pragma unroll
    for (int mask = 1; mask < 16; mask <<= 1) {
#pragma unroll
        for (int m = 0; m < 4; ++m)
#pragma unroll
            for (int j = 0; j < 4; ++j) {
                s1[m][j] += __shfl_xor(s1[m][j], mask, 16);
                s2[m][j] += __shfl_xor(s2[m][j], mask, 16);
            }
    }

    float* sred = (float*)&lds[16384];  // [2 stat][2 wn][128 rows]
    if (r == 0) {
#pragma unroll
        for (int m = 0; m < 4; ++m)
#pragma unroll
            for (int j = 0; j < 4; ++j) {
                int row = wm * 64 + m * 16 + h * 4 + j;
                sred[(0 * 2 + wn) * 128 + row] = s1[m][j];
                sred[(1 * 2 + wn) * 128 + row] = s2[m][j];
            }
    }
    __syncthreads();

    const size_t orow0 = (size_t)brow * BM;
#pragma unroll
    for (int m = 0; m < 4; ++m)
#pragma unroll
        for (int j = 0; j < 4; ++j) {
            int row = wm * 64 + m * 16 + h * 4 + j;
            float mu = (sred[0 * 128 + row] + sred[1 * 128 + row]) * (1.f / 128.f);
            float ex2 = (sred[2 * 128 + row] + sred[3 * 128 + row]) * (1.f / 128.f);
            float var = ex2 - mu * mu;
            float rs = rsqrtf(var + 1e-5f);
            float* orow = out + (orow0 + row) * N_DIM;
#pragma unroll
            for (int n = 0; n < 4; ++n) {
                int col = colbase + n * 16 + r;
                orow[col] = (acc[m][n][j] - mu) * rs * gwv[n] + gbv[n];
            }
        }
}

extern "C" void kernel_launch(void* const* d_in, const int* in_sizes, int n_in,
                              void* d_out, int out_size, void* d_ws, size_t ws_size,
                              hipStream_t stream) {
    const float* x        = (const float*)d_in[0];
    const float* weight   = (const float*)d_in[1];
    const float* bias_lin = (const float*)d_in[2];
    const float* bias_ex  = (const float*)d_in[3];
    const float* gn_w     = (const float*)d_in[4];
    const float* gn_b     = (const float*)d_in[5];
    float* out = (float*)d_out;

    ushort* xb = (ushort*)d_ws;                     // 32 MiB bf16
    ushort* wb = xb + (size_t)M_DIM * K_DIM;        // 16 MiB bf16

    {
        int n8 = (M_DIM * K_DIM) / 8;
        f32_to_bf16_k<<<n8 / 256, 256, 0, stream>>>(x, xb, n8);
    }
    {
        int n8 = (N_DIM * K_DIM) / 8;
        f32_to_bf16_k<<<n8 / 256, 256, 0, stream>>>(weight, wb, n8);
    }

    // dynamic LDS: 16KB A + 16KB B + 2KB stats = 34816 B  (-> 4 blocks/CU)
    const size_t ldsB = 16384 * sizeof(ushort) + 512 * sizeof(float);
    dim3 grid((M_DIM / BM) * (N_DIM / BN));  // 2048 blocks
    gemm_swish_gn<<<grid, 256, ldsB, stream>>>(xb, wb, bias_lin, bias_ex, gn_w, gn_b, out);
}